// Round 9
// baseline (501.042 us; speedup 1.0000x reference)
//
#include <hip/hip_runtime.h>
#include <hip/hip_bf16.h>
#include <math.h>

typedef __bf16 bf16;
typedef bf16 bf16x8 __attribute__((ext_vector_type(8)));
typedef bf16 bf16x4 __attribute__((ext_vector_type(4)));
typedef float f32x4 __attribute__((ext_vector_type(4)));

#define MFMA16(a, b, c) __builtin_amdgcn_mfma_f32_16x16x32_bf16(a, b, c, 0, 0, 0)

// XOR-swizzle on 16B chunks within a row: breaks power-of-2 row-stride bank aliasing.
__device__ __forceinline__ uint32_t swz(uint32_t base, uint32_t row, uint32_t rs, uint32_t cb) {
    return base + row * rs + (((cb >> 4) ^ (row & 7u)) << 4) + (cb & 15u);
}

// async global->LDS, 16B per lane. LDS dest = wave-uniform base + lane*16 (linear).
__device__ __forceinline__ void gload16(const void* g, void* l) {
    __builtin_amdgcn_global_load_lds((const __attribute__((address_space(1))) void*)g,
                                     (__attribute__((address_space(3))) void*)l, 16, 0, 0);
}

// N256 GEMM template v2 (ALL four GEMMs): 128x256 tile, 8 waves, wave tile
// 64x64, BK=32. 2-deep double-buffer, drain vmcnt(0) per iter. LDS 48KB:
//   A: ib*8192   [0,16384);  B: 16384+ib*16384  [16384,49152)
// 48KB + 64 VGPR -> 3 blocks/CU (6 waves/SIMD): cross-block TLP covers the
// per-iter drain (m97 regime). LN1/LN2 are DE-FUSED into row-wave kernels.

// Scratch map (row r = one of 32768 tokens):
//  src  slice r*2048B: [0,1024)=x_bf16 (xcvt; residual for outproj; dead after)
//                      -> h[1024:1536] (ff1)
//                      [1024,2048)=x1 bf16 (ln1; read ff1 A, ff2-residual)
//  dout slice r*2048B: [0,1024)=k, [1024,2048)=v (qkv; dead after attn)
//                      -> y1 f32 row (outproj; dead after ln1)
//                      -> h[0:1024] (ff1) -> y/out f32 row (ff2; ln2 in place)
//  ws: [0,6.3MB)=bf16 weights; [6.3,39.8MB) r*1024B: q (qkv) -> O (attn, same
//      block/cols) -> h[1536:2048] (ff1)
// Weight regions (bf16 elems), k-tile-major "LDS image", ALL 16KB tiles:
//  unit u: tile=u>>10, c=(u>>8)&3, nn=u&255
//  Wqkv' [0,786432):       96 tiles; n=(tile>>4)*256+nn, k=(tile&15)*32+c*8
//  Wout' [786432,1048576): 32 tiles; n=(tile>>4)*256+nn, k=(tile&15)*32+c*8
//  W1'  [1048576,2097152):128 tiles; n=(tile>>4)*256+nn, k=(tile&15)*32+c*8
//  W2'  [2097152,3145728):128 tiles; n=(tile>>6)*256+nn, k=(tile&63)*32+c*8

// ---------- weights f32 -> bf16, k-tile-major repack ----------
__global__ void wcvt_kernel(const float* __restrict__ wqkv, const float* __restrict__ wout,
                            const float* __restrict__ w1f, const float* __restrict__ w2f,
                            bf16* __restrict__ o) {
    int i = blockIdx.x * blockDim.x + threadIdx.x;  // one 8-elem unit
    const float* s;
    int soff, doff;
    if (i < 98304) {  // Wqkv: [1536][512] -> 96 16KB tiles
        int u = i;
        int tile = u >> 10, c = (u >> 8) & 3, nn = u & 255;
        int n = (tile >> 4) * 256 + nn;
        int k = (tile & 15) * 32 + c * 8;
        s = wqkv; soff = n * 512 + k; doff = u * 8;
    } else if (i < 131072) {  // Wout: [512][512] -> 32 16KB tiles (tile=cb*16+t)
        int u = i - 98304;
        int tile = u >> 10, c = (u >> 8) & 3, nn = u & 255;
        int n = (tile >> 4) * 256 + nn;
        int k = (tile & 15) * 32 + c * 8;
        s = wout; soff = n * 512 + k; doff = 786432 + u * 8;
    } else if (i < 262144) {  // W1: [2048][512] -> 128 16KB tiles
        int u = i - 131072;
        int tile = u >> 10, c = (u >> 8) & 3, nn = u & 255;
        int n = (tile >> 4) * 256 + nn;
        int k = (tile & 15) * 32 + c * 8;
        s = w1f; soff = n * 512 + k; doff = 1048576 + u * 8;
    } else {  // W2: [512][2048] -> 128 16KB tiles (tile = cb*64 + t)
        int u = i - 262144;
        int tile = u >> 10, c = (u >> 8) & 3, nn = u & 255;
        int n = (tile >> 6) * 256 + nn;
        int k = (tile & 63) * 32 + c * 8;
        s = w2f; soff = n * 2048 + k; doff = 2097152 + u * 8;
    }
    float4 v0 = *(const float4*)(s + soff);
    float4 v1 = *(const float4*)(s + soff + 4);
    bf16x8 h = { (bf16)v0.x, (bf16)v0.y, (bf16)v0.z, (bf16)v0.w,
                 (bf16)v1.x, (bf16)v1.y, (bf16)v1.z, (bf16)v1.w };
    *(bf16x8*)(o + doff) = h;
}

// ---------- src f32 -> bf16 in place (row-aligned slot; wave per row) ----------
__global__ void xcvt_kernel(float* __restrict__ src) {
    int row = blockIdx.x * 4 + (threadIdx.x >> 6);
    int l = threadIdx.x & 63;
    float* rp = src + (size_t)row * 512 + l * 8;
    float4 v0 = *(const float4*)rp;
    float4 v1 = *(const float4*)(rp + 4);
    asm volatile("s_waitcnt vmcnt(0)" ::: "memory");  // all wave reads before any write
    bf16x8 h = { (bf16)v0.x, (bf16)v0.y, (bf16)v0.z, (bf16)v0.w,
                 (bf16)v1.x, (bf16)v1.y, (bf16)v1.z, (bf16)v1.w };
    *(bf16x8*)((bf16*)(src + (size_t)row * 512) + l * 8) = h;
}

// ---- N256 main loop v2: 2-deep, drain vmcnt(0) per iter (3 blocks/CU) ----
// Needs STAGE_A(ib,t) (1 gload/wave) and STAGE_B2(ib,t,j) (j=0,1) in scope.
#define N256_LOOP(NT)                                                                  \
    int ib = 0;                                                                        \
    _Pragma("unroll 1")                                                                \
    for (int t = 0; t < (NT); ++t) {                                                   \
        if (t + 1 < (NT)) { STAGE_A(ib ^ 1, t + 1); STAGE_B2(ib ^ 1, t + 1, 0); STAGE_B2(ib ^ 1, t + 1, 1); } \
        const uint32_t A0 = (uint32_t)ib * 8192u;                                      \
        const uint32_t B0 = 16384u + (uint32_t)ib * 16384u;                            \
        bf16x8 a[4], b[4];                                                             \
        _Pragma("unroll")                                                              \
        for (int i = 0; i < 4; ++i)                                                    \
            a[i] = *(const bf16x8*)(smem + A0 + quad * 2048 + (wm * 64 + i * 16 + l16) * 16); \
        _Pragma("unroll")                                                              \
        for (int nt = 0; nt < 4; ++nt)                                                 \
            b[nt] = *(const bf16x8*)(smem + B0 + quad * 4096 + (wn * 64 + nt * 16 + l16) * 16); \
        _Pragma("unroll")                                                              \
        for (int nt = 0; nt < 4; ++nt)                                                 \
            _Pragma("unroll")                                                          \
            for (int i = 0; i < 4; ++i) acc[i][nt] = MFMA16(a[i], b[nt], acc[i][nt]);  \
        asm volatile("s_waitcnt vmcnt(0)" ::: "memory");                               \
        __builtin_amdgcn_s_barrier();                                                  \
        ib ^= 1;                                                                       \
    }

// ---------- qkv GEMM: M=32768 N=1536 K=512; 128x256 tile, grid (256,6) ----------
extern "C" __global__ __launch_bounds__(512, 4)
void qkv_kernel(const char* __restrict__ xb, const char* __restrict__ Wqkvp,
                const float* __restrict__ bqkv, char* __restrict__ qOb,
                char* __restrict__ kvb) {
    extern __shared__ char smem[];
    const int tid = threadIdx.x;
    const int w = tid >> 6, lane = tid & 63, l16 = lane & 15, quad = lane >> 4;
    const int wm = w >> 2, wn = w & 3;
    const int mb = blockIdx.x, cb = blockIdx.y;

    f32x4 acc[4][4];
#pragma unroll
    for (int i = 0; i < 4; ++i)
#pragma unroll
        for (int nt = 0; nt < 4; ++nt) acc[i][nt] = (f32x4){0.f, 0.f, 0.f, 0.f};

#define STAGE_A(ib_, t_)                                                               \
    {                                                                                  \
        int ca = w >> 1, rg = w & 1;                                                   \
        gload16(xb + (size_t)(mb * 128 + rg * 64 + lane) * 2048 + (t_) * 64 + ca * 16, \
                smem + (uint32_t)(ib_) * 8192u + ca * 2048 + rg * 1024);               \
    }
#define STAGE_B2(ib_, t_, j_)                                                          \
    {                                                                                  \
        int idx = w * 2 + (j_), c = idx >> 2, ng = idx & 3;                            \
        gload16(Wqkvp + (size_t)(cb * 16 + (t_)) * 16384 + c * 4096 + ng * 1024 + lane * 16, \
                smem + 16384u + (uint32_t)(ib_) * 16384u + (uint32_t)c * 4096 + (uint32_t)ng * 1024); \
    }

    STAGE_A(0, 0); STAGE_B2(0, 0, 0); STAGE_B2(0, 0, 1);
    asm volatile("s_waitcnt vmcnt(0)" ::: "memory");
    __builtin_amdgcn_s_barrier();

    N256_LOOP(16)
#undef STAGE_A
#undef STAGE_B2

    // epilogue: bias; per-i 16x64 transpose through 2KB wave scratch (dead B region)
    const uint32_t sb = 16384u + (uint32_t)w * 2048u;
#pragma unroll
    for (int i = 0; i < 4; ++i) {
#pragma unroll
        for (int nt = 0; nt < 4; ++nt) {
            float bb = bqkv[cb * 256 + wn * 64 + nt * 16 + l16];
#pragma unroll
            for (int r = 0; r < 4; ++r)
                *(bf16*)(smem + swz(sb, quad * 4 + r, 128, (nt * 16 + l16) * 2)) =
                    (bf16)(acc[i][nt][r] + bb);
        }
        asm volatile("s_waitcnt lgkmcnt(0)" ::: "memory");
#pragma unroll
        for (int t2 = 0; t2 < 2; ++t2) {
            int row = t2 * 8 + (lane >> 3), ch = lane & 7;
            bf16x8 v = *(bf16x8*)(smem + swz(sb, row, 128, ch * 16));
            size_t row_g = (size_t)(mb * 128 + wm * 64 + i * 16 + row);
            int cbyte = wn * 128 + ch * 16;  // within this cb's 512B col-slice
            if (cb < 2)      *(bf16x8*)(qOb + row_g * 1024 + cb * 512 + cbyte) = v;
            else if (cb < 4) *(bf16x8*)(kvb + row_g * 2048 + (cb - 2) * 512 + cbyte) = v;
            else             *(bf16x8*)(kvb + row_g * 2048 + 1024 + (cb - 4) * 512 + cbyte) = v;
        }
        asm volatile("s_waitcnt lgkmcnt(0)" ::: "memory");
    }
}

// ---------- attention: one block per (window, head) ----------
#define AVT 0u       // vT 64x128 bf16 rs=256B (16KB)
#define ASCR 16384u  // 8 waves x 2KB transpose scratch
extern "C" __global__ __launch_bounds__(512, 4)
void attn_kernel(char* __restrict__ qOb, const char* __restrict__ kvb) {
    extern __shared__ char smem[];
    const int tid = threadIdx.x;
    const int wid = tid >> 6, lane = tid & 63, l16 = lane & 15, quad = lane >> 4;
    const int win = blockIdx.x >> 3, head = blockIdx.x & 7;
    const size_t wrow0 = (size_t)win * 128;
    f32x4 zero4 = { 0.f, 0.f, 0.f, 0.f };

    // stage vT[dim][key] from v rows
    {
        int key = tid >> 2, d0 = (tid & 3) * 16;
        const char* vs = kvb + (wrow0 + key) * 2048 + 1024 + head * 128 + d0 * 2;
#pragma unroll
        for (int j = 0; j < 2; ++j) {
            bf16x8 v = *(const bf16x8*)(vs + j * 16);
#pragma unroll
            for (int e = 0; e < 8; ++e)
                *(bf16*)(smem + swz(AVT, d0 + j * 8 + e, 256, key * 2)) = v[e];
        }
    }
    __syncthreads();  // only barrier in this kernel

    // q fragments (A layout, direct from global)
    bf16x8 qf[2];
#pragma unroll
    for (int ks = 0; ks < 2; ++ks)
        qf[ks] = *(const bf16x8*)(qOb + (wrow0 + wid * 16 + l16) * 1024 + head * 128 + ks * 64 + quad * 16);

    // scores (k B-frags direct from global)
    f32x4 sa[8];
#pragma unroll
    for (int nt = 0; nt < 8; ++nt) sa[nt] = zero4;
#pragma unroll
    for (int nt = 0; nt < 8; ++nt)
#pragma unroll
        for (int ks = 0; ks < 2; ++ks) {
            bf16x8 kb = *(const bf16x8*)(kvb + (wrow0 + nt * 16 + l16) * 2048 + head * 128 + ks * 64 + quad * 16);
            sa[nt] = MFMA16(qf[ks], kb, sa[nt]);
        }
#pragma unroll
    for (int nt = 0; nt < 8; ++nt) sa[nt] *= 0.125f;
#pragma unroll
    for (int r = 0; r < 4; ++r) {
        float m = sa[0][r];
#pragma unroll
        for (int nt = 1; nt < 8; ++nt) m = fmaxf(m, sa[nt][r]);
#pragma unroll
        for (int sft = 1; sft < 16; sft <<= 1) m = fmaxf(m, __shfl_xor(m, sft, 64));
        float s = 0.f;
#pragma unroll
        for (int nt = 0; nt < 8; ++nt) {
            float e = __expf(sa[nt][r] - m);
            sa[nt][r] = e;
            s += e;
        }
#pragma unroll
        for (int sft = 1; sft < 16; sft <<= 1) s += __shfl_xor(s, sft, 64);
        float inv = 1.0f / s;
#pragma unroll
        for (int nt = 0; nt < 8; ++nt) sa[nt][r] *= inv;
    }

    // P C->A transpose through wave-private scratch
    const uint32_t sb = ASCR + (uint32_t)wid * 2048;
    bf16x8 pf[4];
#pragma unroll
    for (int hf = 0; hf < 2; ++hf) {
#pragma unroll
        for (int nt = 0; nt < 4; ++nt)
#pragma unroll
            for (int r = 0; r < 4; ++r)
                *(bf16*)(smem + swz(sb, quad * 4 + r, 128, (nt * 16 + l16) * 2)) = (bf16)sa[hf * 4 + nt][r];
        asm volatile("s_waitcnt lgkmcnt(0)" ::: "memory");
#pragma unroll
        for (int ks = 0; ks < 2; ++ks)
            pf[hf * 2 + ks] = *(bf16x8*)(smem + swz(sb, l16, 128, ks * 64 + quad * 16));
        asm volatile("s_waitcnt lgkmcnt(0)" ::: "memory");
    }

    // O = P @ V
    f32x4 ov[4];
#pragma unroll
    for (int nt = 0; nt < 4; ++nt) {
        ov[nt] = zero4;
#pragma unroll
        for (int ks = 0; ks < 4; ++ks) {
            bf16x8 vb = *(bf16x8*)(smem + swz(AVT, nt * 16 + l16, 256, ks * 64 + quad * 16));
            ov[nt] = MFMA16(pf[ks], vb, ov[nt]);
        }
    }
    // O store via transpose: two 32-col halves through 2KB wave scratch (rs=128)
#pragma unroll
    for (int hf = 0; hf < 2; ++hf) {
#pragma unroll
        for (int nt = 0; nt < 2; ++nt)
#pragma unroll
            for (int r = 0; r < 4; ++r)
                *(bf16*)(smem + swz(sb, quad * 4 + r, 128, (nt * 16 + l16) * 2)) = (bf16)ov[hf * 2 + nt][r];
        asm volatile("s_waitcnt lgkmcnt(0)" ::: "memory");
        {
            int row = lane >> 2, ch = lane & 3;
            bf16x8 v = *(bf16x8*)(smem + swz(sb, row, 128, ch * 16));
            *(bf16x8*)(qOb + (wrow0 + wid * 16 + row) * 1024 + head * 128 + hf * 64 + ch * 16) = v;
        }
        asm volatile("s_waitcnt lgkmcnt(0)" ::: "memory");
    }
}

// ---------- out-proj: M=32768 N=512 K=512; 128x256 tile, grid (256,2) ----------
// N256 template. Epilogue: y1 = acc + bout + x(residual) -> f32 doutb (k/v dead).
// LN1 de-fused into ln1_kernel.
extern "C" __global__ __launch_bounds__(512, 4)
void outproj_kernel(const char* __restrict__ srcb, const char* __restrict__ qOb,
                    const char* __restrict__ Woutp, const float* __restrict__ bout,
                    char* __restrict__ doutb) {
    extern __shared__ char smem[];
    const int tid = threadIdx.x;
    const int w = tid >> 6, lane = tid & 63, l16 = lane & 15, quad = lane >> 4;
    const int wm = w >> 2, wn = w & 3;
    const int mb = blockIdx.x, cb = blockIdx.y;

    f32x4 acc[4][4];
#pragma unroll
    for (int i = 0; i < 4; ++i)
#pragma unroll
        for (int nt = 0; nt < 4; ++nt) acc[i][nt] = (f32x4){0.f, 0.f, 0.f, 0.f};

#define STAGE_A(ib_, t_)                                                               \
    {                                                                                  \
        int ca = w >> 1, rg = w & 1;                                                   \
        gload16(qOb + (size_t)(mb * 128 + rg * 64 + lane) * 1024 + (t_) * 64 + ca * 16, \
                smem + (uint32_t)(ib_) * 8192u + ca * 2048 + rg * 1024);               \
    }
#define STAGE_B2(ib_, t_, j_)                                                          \
    {                                                                                  \
        int idx = w * 2 + (j_), c = idx >> 2, ng = idx & 3;                            \
        gload16(Woutp + (size_t)(cb * 16 + (t_)) * 16384 + c * 4096 + ng * 1024 + lane * 16, \
                smem + 16384u + (uint32_t)(ib_) * 16384u + (uint32_t)c * 4096 + (uint32_t)ng * 1024); \
    }

    STAGE_A(0, 0); STAGE_B2(0, 0, 0); STAGE_B2(0, 0, 1);
    asm volatile("s_waitcnt vmcnt(0)" ::: "memory");
    __builtin_amdgcn_s_barrier();

    N256_LOOP(16)
#undef STAGE_A
#undef STAGE_B2

    // epilogue: y1 = acc + bias + x -> f32 into doutb (k/v region, dead post-attn)
#pragma unroll
    for (int nt = 0; nt < 4; ++nt) {
        int col = cb * 256 + wn * 64 + nt * 16 + l16;
        float bb = bout[col];
#pragma unroll
        for (int i = 0; i < 4; ++i)
#pragma unroll
            for (int r = 0; r < 4; ++r) {
                int row = mb * 128 + wm * 64 + i * 16 + quad * 4 + r;
                float xv = (float)*(const bf16*)(srcb + (size_t)row * 2048 + col * 2);
                *(float*)(doutb + (size_t)row * 2048 + col * 4) = acc[i][nt][r] + bb + xv;
            }
    }
}

// ---------- LN1: read f32 y1 (doutb), write bf16 x1 -> srcb[1024:2048) ----------
extern "C" __global__ __launch_bounds__(256)
void ln1_kernel(const float* __restrict__ y1, char* __restrict__ srcb,
                const float* __restrict__ g1, const float* __restrict__ be1) {
    int row = blockIdx.x * 4 + (threadIdx.x >> 6);
    int lane = threadIdx.x & 63;
    const float* rp = y1 + (size_t)row * 512 + lane * 8;
    float4 v0 = *(const float4*)rp;
    float4 v1 = *(const float4*)(rp + 4);
    float s = v0.x + v0.y + v0.z + v0.w + v1.x + v1.y + v1.z + v1.w;
    float s2 = v0.x * v0.x + v0.y * v0.y + v0.z * v0.z + v0.w * v0.w +
               v1.x * v1.x + v1.y * v1.y + v1.z * v1.z + v1.w * v1.w;
#pragma unroll
    for (int sft = 1; sft < 64; sft <<= 1) {
        s += __shfl_xor(s, sft, 64);
        s2 += __shfl_xor(s2, sft, 64);
    }
    float mu = s * (1.0f / 512.0f);
    float var = s2 * (1.0f / 512.0f) - mu * mu;
    float rstd = rsqrtf(var + 1e-5f);
    const float* gp = g1 + lane * 8;
    const float* bp = be1 + lane * 8;
    bf16x8 h;
    h[0] = (bf16)((v0.x - mu) * rstd * gp[0] + bp[0]);
    h[1] = (bf16)((v0.y - mu) * rstd * gp[1] + bp[1]);
    h[2] = (bf16)((v0.z - mu) * rstd * gp[2] + bp[2]);
    h[3] = (bf16)((v0.w - mu) * rstd * gp[3] + bp[3]);
    h[4] = (bf16)((v1.x - mu) * rstd * gp[4] + bp[4]);
    h[5] = (bf16)((v1.y - mu) * rstd * gp[5] + bp[5]);
    h[6] = (bf16)((v1.z - mu) * rstd * gp[6] + bp[6]);
    h[7] = (bf16)((v1.w - mu) * rstd * gp[7] + bp[7]);
    *(bf16x8*)(srcb + (size_t)row * 2048 + 1024 + lane * 16) = h;
}

// ---------- FF1: M=32768 N=2048 K=512; 128x256 tile, grid (256,8) ----------
extern "C" __global__ __launch_bounds__(512, 4)
void ff1_kernel(char* __restrict__ srcb, const char* __restrict__ W1p,
                const float* __restrict__ b1, char* __restrict__ doutb,
                char* __restrict__ wsOb) {
    extern __shared__ char smem[];
    const int tid = threadIdx.x;
    const int w = tid >> 6, lane = tid & 63, l16 = lane & 15, quad = lane >> 4;
    const int wm = w >> 2, wn = w & 3;
    const int mb = blockIdx.x, cb = blockIdx.y;

    f32x4 acc[4][4];
#pragma unroll
    for (int i = 0; i < 4; ++i)
#pragma unroll
        for (int nt = 0; nt < 4; ++nt) acc[i][nt] = (f32x4){0.f, 0.f, 0.f, 0.f};

#define STAGE_A(ib_, t_)                                                               \
    {                                                                                  \
        int ca = w >> 1, rg = w & 1;                                                   \
        gload16(srcb + (size_t)(mb * 128 + rg * 64 + lane) * 2048 + 1024 + (t_) * 64 + ca * 16, \
                smem + (uint32_t)(ib_) * 8192u + ca * 2048 + rg * 1024);               \
    }
#define STAGE_B2(ib_, t_, j_)                                                          \
    {                                                                                  \
        int idx = w * 2 + (j_), c = idx >> 2, ng = idx & 3;                            \
        gload16(W1p + (size_t)(cb * 16 + (t_)) * 16384 + c * 4096 + ng * 1024 + lane * 16, \
                smem + 16384u + (uint32_t)(ib_) * 16384u + (uint32_t)c * 4096 + (uint32_t)ng * 1024); \
    }

    STAGE_A(0, 0); STAGE_B2(0, 0, 0); STAGE_B2(0, 0, 1);
    asm volatile("s_waitcnt vmcnt(0)" ::: "memory");
    __builtin_amdgcn_s_barrier();

    N256_LOOP(16)
#undef STAGE_A
#undef STAGE_B2

    // epilogue: bias+relu; per-i 16x64 transpose through 2KB wave scratch
    const uint32_t sb = 16384u + (uint32_t)w * 2048u;
#pragma unroll
    for (int i = 0; i < 4; ++i) {
#pragma unroll
        for (int nt = 0; nt < 4; ++nt) {
            float bb = b1[cb * 256 + wn * 64 + nt * 16 + l16];
#pragma unroll
            for (int r = 0; r < 4; ++r)
                *(bf16*)(smem + swz(sb, quad * 4 + r, 128, (nt * 16 + l16) * 2)) =
                    (bf16)fmaxf(acc[i][nt][r] + bb, 0.0f);
        }
        asm volatile("s_waitcnt lgkmcnt(0)" ::: "memory");
#pragma unroll
        for (int t2 = 0; t2 < 2; ++t2) {
            int row = t2 * 8 + (lane >> 3), ch = lane & 7;
            bf16x8 v = *(bf16x8*)(smem + swz(sb, row, 128, ch * 16));
            size_t row_g = (size_t)(mb * 128 + wm * 64 + i * 16 + row);
            int cbyte = wn * 128 + ch * 16;  // within this cb's 512B col-slice
            if (cb < 4)      *(bf16x8*)(doutb + row_g * 2048 + cb * 512 + cbyte) = v;
            else if (cb < 6) *(bf16x8*)(srcb + row_g * 2048 + (cb - 4) * 512 + cbyte) = v;
            else             *(bf16x8*)(wsOb + row_g * 1024 + (cb - 6) * 512 + cbyte) = v;
        }
        asm volatile("s_waitcnt lgkmcnt(0)" ::: "memory");
    }
}

// ---------- FF2: M=32768 N=512 K=2048; 128x256 tile, grid (256,2) ----------
// Epilogue: y = acc + b2 + x1 -> f32 doutb. LN2 de-fused into ln2_kernel.
extern "C" __global__ __launch_bounds__(512, 4)
void ff2_kernel(char* __restrict__ doutb, const char* __restrict__ srcb,
                const char* __restrict__ wsOb, const char* __restrict__ W2p,
                const float* __restrict__ b2) {
    extern __shared__ char smem[];
    const int tid = threadIdx.x;
    const int w = tid >> 6, lane = tid & 63, l16 = lane & 15, quad = lane >> 4;
    const int wm = w >> 2, wn = w & 3;
    const int mb = blockIdx.x, cb = blockIdx.y;

    f32x4 acc[4][4];
#pragma unroll
    for (int i = 0; i < 4; ++i)
#pragma unroll
        for (int nt = 0; nt < 4; ++nt) acc[i][nt] = (f32x4){0.f, 0.f, 0.f, 0.f};

#define STAGE_A(ib_, t_)                                                               \
    {                                                                                  \
        const char* hb; int rstride, koffb;                                            \
        if ((t_) < 32)      { hb = doutb; rstride = 2048; koffb = (t_) * 64; }         \
        else if ((t_) < 48) { hb = srcb;  rstride = 2048; koffb = ((t_) - 32) * 64; }  \
        else                { hb = wsOb;  rstride = 1024; koffb = ((t_) - 48) * 64; }  \
        int ca = w >> 1, rg = w & 1;                                                   \
        gload16(hb + (size_t)(mb * 128 + rg * 64 + lane) * rstride + koffb + ca * 16,  \
                smem + (uint32_t)(ib_) * 8192u + ca * 2048 + rg * 1024);               \
    }
#define STAGE_B2(ib_, t_, j_)                                                          \
    {                                                                                  \
        int idx = w * 2 + (j_), c = idx >> 2, ng = idx & 3;                            \
        gload16(W2p + (size_t)(cb * 64 + (t_)) * 16384 + c * 4096 + ng * 1024 + lane * 16, \
                smem + 16384u + (uint32_t)(ib_) * 16384u + (uint32_t)c * 4096 + (uint32_t)ng * 1024); \
    }

    STAGE_A(0, 0); STAGE_B2(0, 0, 0); STAGE_B2(0, 0, 1);
    asm volatile("s_waitcnt vmcnt(0)" ::: "memory");
    __builtin_amdgcn_s_barrier();

    N256_LOOP(64)
#undef STAGE_A
#undef STAGE_B2

    // epilogue: bias + residual(x1 bf16) -> f32 y into doutb (own rows only;
    // all this block's h reads from doutb finished above)
#pragma unroll
    for (int nt = 0; nt < 4; ++nt) {
        int col = cb * 256 + wn * 64 + nt * 16 + l16;
        float bb = b2[col];
#pragma unroll
        for (int i = 0; i < 4; ++i)
#pragma unroll
            for (int r = 0; r < 4; ++r) {
                int row = mb * 128 + wm * 64 + i * 16 + quad * 4 + r;
                float x1v = (float)*(const bf16*)(srcb + (size_t)row * 2048 + 1024 + col * 2);
                *(float*)(doutb + (size_t)row * 2048 + col * 4) = acc[i][nt][r] + bb + x1v;
            }
    }
}

// ---------- LN2: in-place row layernorm on f32 y (wave per row) ----------
extern "C" __global__ __launch_bounds__(256)
void ln2_kernel(float* __restrict__ y, const float* __restrict__ g2,
                const float* __restrict__ be2) {
    int row = blockIdx.x * 4 + (threadIdx.x >> 6);
    int lane = threadIdx.x & 63;
    float* rp = y + (size_t)row * 512 + lane * 8;
    float4 v0 = *(const float4*)rp;
    float4 v1 = *(const float4*)(rp + 4);
    float s = v0.x + v0.y + v0.z + v0.w + v1.x + v1.y + v1.z + v1.w;
    float s2 = v0.x * v0.x + v0.y * v0.y + v0.z * v0.z + v0.w * v0.w +
               v1.x * v1.x + v1.y * v1.y + v1.z * v1.z + v1.w * v1.w;
#pragma unroll
    for (int sft = 1; sft < 64; sft <<= 1) {
        s += __shfl_xor(s, sft, 64);
        s2 += __shfl_xor(s2, sft, 64);
    }
    float mu = s * (1.0f / 512.0f);
    float var = s2 * (1.0f / 512.0f) - mu * mu;
    float rstd = rsqrtf(var + 1e-5f);
    const float* gp = g2 + lane * 8;
    const float* bp = be2 + lane * 8;
    float4 o0, o1;
    o0.x = (v0.x - mu) * rstd * gp[0] + bp[0];
    o0.y = (v0.y - mu) * rstd * gp[1] + bp[1];
    o0.z = (v0.z - mu) * rstd * gp[2] + bp[2];
    o0.w = (v0.w - mu) * rstd * gp[3] + bp[3];
    o1.x = (v1.x - mu) * rstd * gp[4] + bp[4];
    o1.y = (v1.y - mu) * rstd * gp[5] + bp[5];
    o1.z = (v1.z - mu) * rstd * gp[6] + bp[6];
    o1.w = (v1.w - mu) * rstd * gp[7] + bp[7];
    *(float4*)rp = o0;
    *(float4*)(rp + 4) = o1;
}

extern "C" void kernel_launch(void* const* d_in, const int* in_sizes, int n_in,
                              void* d_out, int out_size, void* d_ws, size_t ws_size,
                              hipStream_t stream) {
    (void)in_sizes; (void)n_in; (void)out_size; (void)ws_size;
    float* src = (float*)d_in[0];
    const float* ipw = (const float*)d_in[1];
    const float* ipb = (const float*)d_in[2];
    const float* ow  = (const float*)d_in[3];
    const float* ob  = (const float*)d_in[4];
    const float* g1  = (const float*)d_in[5];
    const float* be1 = (const float*)d_in[6];
    const float* w1  = (const float*)d_in[7];
    const float* b1  = (const float*)d_in[8];
    const float* w2  = (const float*)d_in[9];
    const float* b2  = (const float*)d_in[10];
    const float* g2  = (const float*)d_in[11];
    const float* be2 = (const float*)d_in[12];
    bf16* ws = (bf16*)d_ws;
    char* srcb = (char*)src;
    char* doutb = (char*)d_out;
    char* qOb = (char*)d_ws + 6291456;  // 33.5 MB q/O/h-tail region

    wcvt_kernel<<<1536, 256, 0, stream>>>(ipw, ow, w1, w2, ws);
    xcvt_kernel<<<8192, 256, 0, stream>>>(src);

    hipFuncSetAttribute((const void*)qkv_kernel, hipFuncAttributeMaxDynamicSharedMemorySize, 49152);
    hipFuncSetAttribute((const void*)attn_kernel, hipFuncAttributeMaxDynamicSharedMemorySize, 32768);
    hipFuncSetAttribute((const void*)outproj_kernel, hipFuncAttributeMaxDynamicSharedMemorySize, 49152);
    hipFuncSetAttribute((const void*)ff1_kernel, hipFuncAttributeMaxDynamicSharedMemorySize, 49152);
    hipFuncSetAttribute((const void*)ff2_kernel, hipFuncAttributeMaxDynamicSharedMemorySize, 49152);

    qkv_kernel<<<dim3(256, 6), 512, 49152, stream>>>(srcb, (const char*)ws, ipb, qOb, doutb);
    attn_kernel<<<2048, 512, 32768, stream>>>(qOb, doutb);
    outproj_kernel<<<dim3(256, 2), 512, 49152, stream>>>(srcb, qOb, (const char*)(ws + 786432), ob, doutb);
    ln1_kernel<<<8192, 256, 0, stream>>>((const float*)doutb, srcb, g1, be1);
    ff1_kernel<<<dim3(256, 8), 512, 49152, stream>>>(srcb, (const char*)(ws + 1048576), b1, doutb, qOb);
    ff2_kernel<<<dim3(256, 2), 512, 49152, stream>>>(doutb, srcb, qOb, (const char*)(ws + 2097152), b2);
    ln2_kernel<<<8192, 256, 0, stream>>>((float*)doutb, g2, be2);
}